// Round 10
// baseline (182.572 us; speedup 1.0000x reference)
//
#include <hip/hip_runtime.h>

#define NB 32768
#define NF 256
#define H1 16
#define H2 8
#define ROWS_PER_BLOCK 1024
#define SLAB 128                      // rows per iteration (2 per lane)
#define ITERS (ROWS_PER_BLOCK / SLAB) // 8
#define FPB 4                         // features (waves) per block
#define NT (FPB * 64)                 // 256 threads

__device__ __forceinline__ float elu_f(float v) {
    return v > 0.0f ? v : (__expf(v) - 1.0f);
}
// force a wave-uniform float into an SGPR
__device__ __forceinline__ float rfl(float v) {
    return __int_as_float(__builtin_amdgcn_readfirstlane(__float_as_int(v)));
}

// One WAVE per feature; lanes = 64 rows, TWO row streams per lane
// (lane, lane+64). R9's register diet (40 VGPR) makes the dual-row state
// fit: ~55 VGPRs < 64-bin. Every SGPR weight and every ds_read_b128 now
// feeds BOTH rows' FMAs -> LDS pipe pressure per element halves, and the
// two independent exp chains double ILP over each wait.
//   - W2 rows 0..7 -> SGPR (readfirstlane); rows 8..15 -> LDS broadcast
//   - b1, W3, b3 -> SGPR; per-lane: w1(16), b2(8), acc0/acc1(16), x-state
__global__ __launch_bounds__(NT, 4)
void z_kernel(const float* __restrict__ x,  const float* __restrict__ W1,
              const float* __restrict__ b1, const float* __restrict__ W2,
              const float* __restrict__ b2, const float* __restrict__ W3,
              const float* __restrict__ b3, float* __restrict__ z_out) {
    const int wave = threadIdx.x >> 6;
    const int lane = threadIdx.x & 63;
    const int f    = blockIdx.y * FPB + wave;
    const int rowBase = blockIdx.x * ROWS_PER_BLOCK;

    __shared__ float lds_w2[FPB][64];        // W2 rows 8..15 per feature

    // ---- stage W2 high half into LDS (16 lanes x float4) ----
    if (lane < 16) {
        const float4 v = reinterpret_cast<const float4*>(W2 + f * H1 * H2 + 64)[lane];
        reinterpret_cast<float4*>(lds_w2[wave])[lane] = v;
    }

    // ---- W2 rows 0..7 -> SGPR ----
    float s_w2[8 * H2];
    {
        const float4* p = reinterpret_cast<const float4*>(W2 + f * H1 * H2);
        #pragma unroll
        for (int i = 0; i < 16; ++i) {
            float4 v = p[i];
            s_w2[4*i]   = rfl(v.x); s_w2[4*i+1] = rfl(v.y);
            s_w2[4*i+2] = rfl(v.z); s_w2[4*i+3] = rfl(v.w);
        }
    }
    // ---- W1 -> per-lane VGPR, b1 -> SGPR (v_fma: 1 SGPR operand) ----
    float w1v[H1], s_b1[H1];
    {
        const float4* pw = reinterpret_cast<const float4*>(W1 + f * H1);
        const float4* pb = reinterpret_cast<const float4*>(b1 + f * H1);
        #pragma unroll
        for (int i = 0; i < 4; ++i) {
            float4 v = pw[i];
            w1v[4*i] = v.x; w1v[4*i+1] = v.y; w1v[4*i+2] = v.z; w1v[4*i+3] = v.w;
        }
        #pragma unroll
        for (int i = 0; i < 4; ++i) {
            float4 v = pb[i];
            s_b1[4*i]   = rfl(v.x); s_b1[4*i+1] = rfl(v.y);
            s_b1[4*i+2] = rfl(v.z); s_b1[4*i+3] = rfl(v.w);
        }
    }
    // ---- b2 -> per-lane VGPR; W3, b3 -> SGPR ----
    float b2v[H2];
    {
        const float4* p = reinterpret_cast<const float4*>(b2 + f * H2);
        float4 v0 = p[0], v1 = p[1];
        b2v[0]=v0.x; b2v[1]=v0.y; b2v[2]=v0.z; b2v[3]=v0.w;
        b2v[4]=v1.x; b2v[5]=v1.y; b2v[6]=v1.z; b2v[7]=v1.w;
    }
    float s_w3[H2];
    {
        const float4* p = reinterpret_cast<const float4*>(W3 + f * H2);
        float4 v0 = p[0], v1 = p[1];
        s_w3[0]=rfl(v0.x); s_w3[1]=rfl(v0.y); s_w3[2]=rfl(v0.z); s_w3[3]=rfl(v0.w);
        s_w3[4]=rfl(v1.x); s_w3[5]=rfl(v1.y); s_w3[6]=rfl(v1.z); s_w3[7]=rfl(v1.w);
    }
    const float s_b3 = rfl(b3[f]);

    __syncthreads();                          // LDS W2 ready

    const float* wbase = lds_w2[wave];

    // two row streams per lane: rows (rowBase+lane) and (rowBase+lane+64)
    int offA = (rowBase + lane) * NF + f;
    int offB = offA + 64 * NF;
    float xa = x[offA];
    float xb = x[offB];

    #pragma unroll 1
    for (int it = 0; it < ITERS; ++it) {
        const int na = offA + SLAB * NF;
        const int nb = offB + SLAB * NF;
        const bool more = (it + 1 < ITERS);
        const float xa2 = x[more ? na : offA];     // prefetch next slab
        const float xb2 = x[more ? nb : offB];

        float acc0[H2], acc1[H2];
        #pragma unroll
        for (int k = 0; k < H2; ++k) { acc0[k] = b2v[k]; acc1[k] = b2v[k]; }

        // ---- W2 rows 0..7: SGPR path (each weight feeds both rows) ----
        #pragma unroll
        for (int h = 0; h < 8; ++h) {
            const float ha = elu_f(fmaf(xa, w1v[h], s_b1[h]));
            const float hb = elu_f(fmaf(xb, w1v[h], s_b1[h]));
            #pragma unroll
            for (int k = 0; k < H2; ++k) {
                const float w = s_w2[h * H2 + k];
                acc0[k] = fmaf(ha, w, acc0[k]);
                acc1[k] = fmaf(hb, w, acc1[k]);
            }
        }

        // ---- W2 rows 8..15: LDS broadcast path, one read serves 2 rows ----
        // opaque per-iteration offset: blocks LICM from hoisting the 16
        // ds_read_b128s out of the row loop (would recreate reg pressure)
        int dsoff = 0;
        asm volatile("" : "+v"(dsoff));
        const float4* wp = reinterpret_cast<const float4*>(wbase + dsoff);
        #pragma unroll
        for (int h = 0; h < 8; ++h) {
            const float4 wlo = wp[2 * h];
            const float4 whi = wp[2 * h + 1];
            const float ha = elu_f(fmaf(xa, w1v[8 + h], s_b1[8 + h]));
            const float hb = elu_f(fmaf(xb, w1v[8 + h], s_b1[8 + h]));
            acc0[0] = fmaf(ha, wlo.x, acc0[0]);  acc1[0] = fmaf(hb, wlo.x, acc1[0]);
            acc0[1] = fmaf(ha, wlo.y, acc0[1]);  acc1[1] = fmaf(hb, wlo.y, acc1[1]);
            acc0[2] = fmaf(ha, wlo.z, acc0[2]);  acc1[2] = fmaf(hb, wlo.z, acc1[2]);
            acc0[3] = fmaf(ha, wlo.w, acc0[3]);  acc1[3] = fmaf(hb, wlo.w, acc1[3]);
            acc0[4] = fmaf(ha, whi.x, acc0[4]);  acc1[4] = fmaf(hb, whi.x, acc1[4]);
            acc0[5] = fmaf(ha, whi.y, acc0[5]);  acc1[5] = fmaf(hb, whi.y, acc1[5]);
            acc0[6] = fmaf(ha, whi.z, acc0[6]);  acc1[6] = fmaf(hb, whi.z, acc1[6]);
            acc0[7] = fmaf(ha, whi.w, acc0[7]);  acc1[7] = fmaf(hb, whi.w, acc1[7]);
        }

        float z0 = s_b3, z1 = s_b3;
        #pragma unroll
        for (int k = 0; k < H2; ++k) {
            z0 = fmaf(elu_f(acc0[k]), s_w3[k], z0);
            z1 = fmaf(elu_f(acc1[k]), s_w3[k], z1);
        }

        z_out[offA] = z0;
        z_out[offB] = z1;
        offA = na; offB = nb; xa = xa2; xb = xb2;
    }
}

// Memory-bound epilogue: w = softplus(theta); y[row] = dot(z[row,:], w) + bias.
#define NT2 256
#define ROWS2 64
__global__ __launch_bounds__(NT2, 4)
void y_kernel(const float* __restrict__ z, const float* __restrict__ theta,
              const float* __restrict__ bias, float* __restrict__ y_out,
              float* __restrict__ w_out) {
    __shared__ __align__(16) float wls[NF];
    const int tid = threadIdx.x;
    {
        const float th = theta[tid];
        const float w  = logf(1.0f + __expf(th));
        wls[tid] = w;
        if (blockIdx.x == 0) w_out[tid] = w;
    }
    __syncthreads();
    const int wave = tid >> 6, lane = tid & 63;
    const float4 w4 = reinterpret_cast<const float4*>(wls)[lane];
    const float biasv = bias[0];
    #pragma unroll 1
    for (int r = 0; r < ROWS2 / 4; ++r) {          // 16 rows per wave
        const int row = blockIdx.x * ROWS2 + wave * (ROWS2 / 4) + r;
        const float4 zv = reinterpret_cast<const float4*>(z + row * NF)[lane];
        float s = zv.x * w4.x + zv.y * w4.y + zv.z * w4.z + zv.w * w4.w;
        #pragma unroll
        for (int o = 32; o > 0; o >>= 1) s += __shfl_down(s, o, 64);
        if (lane == 0) y_out[row] = s + biasv;
    }
}

extern "C" void kernel_launch(void* const* d_in, const int* in_sizes, int n_in,
                              void* d_out, int out_size, void* d_ws, size_t ws_size,
                              hipStream_t stream) {
    const float* x     = (const float*)d_in[0];
    const float* W1    = (const float*)d_in[1];
    const float* b1    = (const float*)d_in[2];
    const float* W2    = (const float*)d_in[3];
    const float* b2    = (const float*)d_in[4];
    const float* W3    = (const float*)d_in[5];
    const float* b3    = (const float*)d_in[6];
    const float* theta = (const float*)d_in[7];
    const float* bias  = (const float*)d_in[8];

    float* y_out = (float*)d_out;                  // [32768]
    float* w_out = y_out + NB;                     // [256]
    float* z_out = w_out + NF;                     // [32768*256]

    dim3 grid1(NB / ROWS_PER_BLOCK, NF / FPB);     // 32 x 64
    z_kernel<<<grid1, NT, 0, stream>>>(x, W1, b1, W2, b2, W3, b3, z_out);
    y_kernel<<<NB / ROWS2, NT2, 0, stream>>>(z_out, theta, bias, y_out, w_out);
}

// Round 11
// 161.270 us; speedup vs baseline: 1.1321x; 1.1321x over previous
//
#include <hip/hip_runtime.h>

#define NB 32768
#define NF 256
#define H1 16
#define H2 8
#define ROWS_PER_BLOCK 1024
#define ITERS (ROWS_PER_BLOCK / 64)   // 16 (one row per lane per iter)
#define FPB 4                         // features (waves) per block
#define NT (FPB * 64)                 // 256 threads

__device__ __forceinline__ float elu_f(float v) {
    return v > 0.0f ? v : (__expf(v) - 1.0f);
}
// force a wave-uniform float into an SGPR
__device__ __forceinline__ float rfl(float v) {
    return __int_as_float(__builtin_amdgcn_readfirstlane(__float_as_int(v)));
}

// One WAVE per feature; lanes = 64 rows (R9 skeleton, proven 83-85us).
// R9 diagnosis: 16 ds_read_b128/row = 192cyc/row on the per-CU LDS pipe vs
// ~1000cyc/row VALU per SIMD -> poorly-overlapped second pipe capped busy at
// ~65%. This round: W2 split three ways to halve LDS and keep regs safe:
//   rows 0..7  -> SGPR (readfirstlane; v_fma takes 1 SGPR operand)
//   rows 8..11 -> LDS broadcast (8 ds_read_b128/row = 96cyc, sub-dominant)
//   rows 12..15-> per-lane VGPR (+32 regs; demand ~80 < budget 102 at
//                 launch_bounds(256,5) -> arch VGPRs, spill-impossible)
// Plus 2-deep x prefetch: 1-row-ahead slack (~1000cyc) == HBM latency with
// zero margin; 2 rows decouples it.
__global__ __launch_bounds__(NT, 5)
void z_kernel(const float* __restrict__ x,  const float* __restrict__ W1,
              const float* __restrict__ b1, const float* __restrict__ W2,
              const float* __restrict__ b2, const float* __restrict__ W3,
              const float* __restrict__ b3, float* __restrict__ z_out) {
    const int wave = threadIdx.x >> 6;
    const int lane = threadIdx.x & 63;
    const int f    = blockIdx.y * FPB + wave;
    const int rowBase = blockIdx.x * ROWS_PER_BLOCK;

    __shared__ float lds_w2[FPB][32];        // W2 rows 8..11 per feature

    // ---- stage W2 rows 8..11 into LDS (8 lanes x float4) ----
    if (lane < 8) {
        const float4 v = reinterpret_cast<const float4*>(W2 + f * H1 * H2 + 64)[lane];
        reinterpret_cast<float4*>(lds_w2[wave])[lane] = v;
    }

    // ---- W2 rows 0..7 -> SGPR ----
    float s_w2[8 * H2];
    {
        const float4* p = reinterpret_cast<const float4*>(W2 + f * H1 * H2);
        #pragma unroll
        for (int i = 0; i < 16; ++i) {
            float4 v = p[i];
            s_w2[4*i]   = rfl(v.x); s_w2[4*i+1] = rfl(v.y);
            s_w2[4*i+2] = rfl(v.z); s_w2[4*i+3] = rfl(v.w);
        }
    }
    // ---- W2 rows 12..15 -> per-lane VGPR (32 floats) ----
    float w2v[32];
    {
        const float4* p = reinterpret_cast<const float4*>(W2 + f * H1 * H2 + 96);
        #pragma unroll
        for (int i = 0; i < 8; ++i) {
            float4 v = p[i];
            w2v[4*i]=v.x; w2v[4*i+1]=v.y; w2v[4*i+2]=v.z; w2v[4*i+3]=v.w;
        }
    }
    // ---- W1 -> per-lane VGPR, b1 -> SGPR ----
    float w1v[H1], s_b1[H1];
    {
        const float4* pw = reinterpret_cast<const float4*>(W1 + f * H1);
        const float4* pb = reinterpret_cast<const float4*>(b1 + f * H1);
        #pragma unroll
        for (int i = 0; i < 4; ++i) {
            float4 v = pw[i];
            w1v[4*i] = v.x; w1v[4*i+1] = v.y; w1v[4*i+2] = v.z; w1v[4*i+3] = v.w;
        }
        #pragma unroll
        for (int i = 0; i < 4; ++i) {
            float4 v = pb[i];
            s_b1[4*i]   = rfl(v.x); s_b1[4*i+1] = rfl(v.y);
            s_b1[4*i+2] = rfl(v.z); s_b1[4*i+3] = rfl(v.w);
        }
    }
    // ---- b2 -> per-lane VGPR; W3, b3 -> SGPR ----
    float b2v[H2];
    {
        const float4* p = reinterpret_cast<const float4*>(b2 + f * H2);
        float4 v0 = p[0], v1 = p[1];
        b2v[0]=v0.x; b2v[1]=v0.y; b2v[2]=v0.z; b2v[3]=v0.w;
        b2v[4]=v1.x; b2v[5]=v1.y; b2v[6]=v1.z; b2v[7]=v1.w;
    }
    float s_w3[H2];
    {
        const float4* p = reinterpret_cast<const float4*>(W3 + f * H2);
        float4 v0 = p[0], v1 = p[1];
        s_w3[0]=rfl(v0.x); s_w3[1]=rfl(v0.y); s_w3[2]=rfl(v0.z); s_w3[3]=rfl(v0.w);
        s_w3[4]=rfl(v1.x); s_w3[5]=rfl(v1.y); s_w3[6]=rfl(v1.z); s_w3[7]=rfl(v1.w);
    }
    const float s_b3 = rfl(b3[f]);

    __syncthreads();                          // LDS W2 ready

    const float* wbase = lds_w2[wave];

    // rolling 2-deep prefetch of this lane's x column
    int off = (rowBase + lane) * NF + f;
    float xv = x[off];
    float xn = x[off + 64 * NF];              // valid: ITERS >= 2

    #pragma unroll 1
    for (int it = 0; it < ITERS; ++it) {
        const int off2 = off + 2 * 64 * NF;
        const float xnn = x[(it + 2 < ITERS) ? off2 : off];  // 2 rows ahead

        float acc[H2];
        #pragma unroll
        for (int k = 0; k < H2; ++k) acc[k] = b2v[k];

        // ---- W2 rows 0..7: SGPR path ----
        #pragma unroll
        for (int h = 0; h < 8; ++h) {
            const float h1 = elu_f(fmaf(xv, w1v[h], s_b1[h]));
            #pragma unroll
            for (int k = 0; k < H2; ++k)
                acc[k] = fmaf(h1, s_w2[h * H2 + k], acc[k]);
        }

        // ---- W2 rows 8..11: LDS broadcast path (8 x ds_read_b128) ----
        // opaque per-iteration offset: blocks LICM from hoisting the reads
        // out of the row loop (would add 32 regs of pressure)
        int dsoff = 0;
        asm volatile("" : "+v"(dsoff));
        const float4* wp = reinterpret_cast<const float4*>(wbase + dsoff);
        #pragma unroll
        for (int h = 0; h < 4; ++h) {
            const float4 wlo = wp[2 * h];
            const float4 whi = wp[2 * h + 1];
            const float h1 = elu_f(fmaf(xv, w1v[8 + h], s_b1[8 + h]));
            acc[0] = fmaf(h1, wlo.x, acc[0]);
            acc[1] = fmaf(h1, wlo.y, acc[1]);
            acc[2] = fmaf(h1, wlo.z, acc[2]);
            acc[3] = fmaf(h1, wlo.w, acc[3]);
            acc[4] = fmaf(h1, whi.x, acc[4]);
            acc[5] = fmaf(h1, whi.y, acc[5]);
            acc[6] = fmaf(h1, whi.z, acc[6]);
            acc[7] = fmaf(h1, whi.w, acc[7]);
        }

        // ---- W2 rows 12..15: per-lane VGPR path ----
        #pragma unroll
        for (int h = 0; h < 4; ++h) {
            const float h1 = elu_f(fmaf(xv, w1v[12 + h], s_b1[12 + h]));
            #pragma unroll
            for (int k = 0; k < H2; ++k)
                acc[k] = fmaf(h1, w2v[h * H2 + k], acc[k]);
        }

        float z = s_b3;
        #pragma unroll
        for (int k = 0; k < H2; ++k)
            z = fmaf(elu_f(acc[k]), s_w3[k], z);

        z_out[off] = z;
        off += 64 * NF; xv = xn; xn = xnn;
    }
}

// Memory-bound epilogue: w = softplus(theta); y[row] = dot(z[row,:], w) + bias.
#define NT2 256
#define ROWS2 64
__global__ __launch_bounds__(NT2, 4)
void y_kernel(const float* __restrict__ z, const float* __restrict__ theta,
              const float* __restrict__ bias, float* __restrict__ y_out,
              float* __restrict__ w_out) {
    __shared__ __align__(16) float wls[NF];
    const int tid = threadIdx.x;
    {
        const float th = theta[tid];
        const float w  = logf(1.0f + __expf(th));
        wls[tid] = w;
        if (blockIdx.x == 0) w_out[tid] = w;
    }
    __syncthreads();
    const int wave = tid >> 6, lane = tid & 63;
    const float4 w4 = reinterpret_cast<const float4*>(wls)[lane];
    const float biasv = bias[0];
    #pragma unroll 1
    for (int r = 0; r < ROWS2 / 4; ++r) {          // 16 rows per wave
        const int row = blockIdx.x * ROWS2 + wave * (ROWS2 / 4) + r;
        const float4 zv = reinterpret_cast<const float4*>(z + row * NF)[lane];
        float s = zv.x * w4.x + zv.y * w4.y + zv.z * w4.z + zv.w * w4.w;
        #pragma unroll
        for (int o = 32; o > 0; o >>= 1) s += __shfl_down(s, o, 64);
        if (lane == 0) y_out[row] = s + biasv;
    }
}

extern "C" void kernel_launch(void* const* d_in, const int* in_sizes, int n_in,
                              void* d_out, int out_size, void* d_ws, size_t ws_size,
                              hipStream_t stream) {
    const float* x     = (const float*)d_in[0];
    const float* W1    = (const float*)d_in[1];
    const float* b1    = (const float*)d_in[2];
    const float* W2    = (const float*)d_in[3];
    const float* b2    = (const float*)d_in[4];
    const float* W3    = (const float*)d_in[5];
    const float* b3    = (const float*)d_in[6];
    const float* theta = (const float*)d_in[7];
    const float* bias  = (const float*)d_in[8];

    float* y_out = (float*)d_out;                  // [32768]
    float* w_out = y_out + NB;                     // [256]
    float* z_out = w_out + NF;                     // [32768*256]

    dim3 grid1(NB / ROWS_PER_BLOCK, NF / FPB);     // 32 x 64
    z_kernel<<<grid1, NT, 0, stream>>>(x, W1, b1, W2, b2, W3, b3, z_out);
    y_kernel<<<NB / ROWS2, NT2, 0, stream>>>(z_out, theta, bias, y_out, w_out);
}